// Round 4
// baseline (426.798 us; speedup 1.0000x reference)
//
#include <hip/hip_runtime.h>

#define SCALE 128
#define GRID_L 131                        // grid side
#define SLAB (GRID_L * GRID_L)            // 17161 floats per x-slab
#define GRID_V (GRID_L * GRID_L * GRID_L)
#define BATCH 16
#define NPTS 32768                        // points per sample (2^15)
#define NCB 32                            // 2 clouds x 16 samples
#define NBINS 132                         // abs x-bin storage stride (used: 0..128)
#define TILE_PAD 17164                    // SLAB + 3 shift pad, mult of 4

typedef float fx4 __attribute__((ext_vector_type(4)));   // nontemporal-store-compatible

// ---------------------------------------------------------------------------
// Kernel 1: fused per-axis min + x-histogram (abs bins) + LAST-BLOCK SCAN.
// 4 points/thread via 3x float4 loads. 256 blocks x 1024 thr.
// After flushing its histogram, each block bumps a device-scope ticket; the
// 256th block performs the exclusive prefix scan for all 32 (cloud,sample)
// rows in parallel (one 32-lane group per cb, shuffle scan) -- removing the
// separate scan dispatch and its 132-deep serial latency chain.
// mins[3] pre-set to 0x7f7f7f7f; counts (+done) pre-set to 0.
// ---------------------------------------------------------------------------
__global__ void __launch_bounds__(1024)
min_hist_scan_kernel(const float* __restrict__ pc,
                     const float* __restrict__ gc,
                     int* __restrict__ mins,
                     int* __restrict__ counts,
                     int* __restrict__ done,
                     int* __restrict__ starts,
                     int* __restrict__ cursor) {
    __shared__ int h[NBINS];
    __shared__ int red[3 * 16];           // per-wave mins, 16 waves
    __shared__ int lastflag;

    for (int t = threadIdx.x; t < NBINS; t += 1024) h[t] = 0;
    __syncthreads();

    const float s = SCALE * 0.5f;
    int blk = blockIdx.x;                          // 256 blocks, 4096 pts each
    const float* src = (blk < 128) ? pc : gc;
    int jbase = (blk & 127) * 4096;
    const fx4* p4 = (const fx4*)(src + (size_t)3 * jbase);
    int t3 = 3 * (int)threadIdx.x;
    fx4 a = p4[t3], b = p4[t3 + 1], c = p4[t3 + 2];

    float xs[4] = {a.x, a.w, b.z, c.y};
    float ys[4] = {a.y, b.x, b.w, c.z};
    float zs[4] = {a.z, b.y, c.x, c.w};
    int m0 = 0x7fffffff, m1 = 0x7fffffff, m2 = 0x7fffffff;
    #pragma unroll
    for (int k = 0; k < 4; ++k) {
        float x = xs[k] * s, y = ys[k] * s, z = zs[k] * s;
        int lx = (int)floorf(x), ly = (int)floorf(y), lz = (int)floorf(z);
        // histogram (padding points masked; mins include ALL points, per ref)
        if (x + y + z != 0.0f) atomicAdd(&h[lx + 64], 1);
        m0 = min(m0, lx); m1 = min(m1, ly); m2 = min(m2, lz);
    }

    // wave-64 min reduction
    #pragma unroll
    for (int off = 32; off > 0; off >>= 1) {
        m0 = min(m0, __shfl_down(m0, off));
        m1 = min(m1, __shfl_down(m1, off));
        m2 = min(m2, __shfl_down(m2, off));
    }
    int wave = threadIdx.x >> 6;
    if ((threadIdx.x & 63) == 0) {
        red[3 * wave + 0] = m0;
        red[3 * wave + 1] = m1;
        red[3 * wave + 2] = m2;
    }
    __syncthreads();

    if (threadIdx.x < 3) {
        int m = red[threadIdx.x];
        #pragma unroll
        for (int w = 1; w < 16; ++w) m = min(m, red[3 * w + threadIdx.x]);
        atomicMin(&mins[threadIdx.x], m);
    }

    // flush histogram; 8 blocks per (cloud,sample)
    int cb = (blk >> 7) * 16 + ((blk & 127) >> 3);
    for (int t = threadIdx.x; t < NBINS; t += 1024) {
        int cnt = h[t];
        if (cnt) atomicAdd(&counts[cb * NBINS + t], cnt);
    }

    // ---- last-block ticket ----
    __threadfence();                      // make our count atomics visible
    __syncthreads();
    if (threadIdx.x == 0) {
        int t = __hip_atomic_fetch_add(done, 1, __ATOMIC_ACQ_REL,
                                       __HIP_MEMORY_SCOPE_AGENT);
        lastflag = (t == 255);            // gridDim.x == 256
    }
    __syncthreads();
    if (!lastflag) return;

    // ---- parallel exclusive scan: 32 groups of 32 lanes, group g = cb g ----
    int g = threadIdx.x >> 5, l = threadIdx.x & 31;
    const int* cnt = counts + g * NBINS;
    int v[5]; int S = 0;
    #pragma unroll
    for (int k = 0; k < 5; ++k) {
        int bbin = 5 * l + k;
        v[k] = (bbin < NBINS)
             ? __hip_atomic_load(&cnt[bbin], __ATOMIC_RELAXED,
                                 __HIP_MEMORY_SCOPE_AGENT) : 0;
        S += v[k];
    }
    int incl = S;
    #pragma unroll
    for (int d = 1; d < 32; d <<= 1) {
        int u = __shfl_up(incl, d, 32);
        if (l >= d) incl += u;
    }
    int off = incl - S;                   // exclusive offset of this lane's chunk
    #pragma unroll
    for (int k = 0; k < 5; ++k) {
        int bbin = 5 * l + k;
        if (bbin < NBINS) {
            starts[g * (NBINS + 1) + bbin] = off;
            cursor[g * NBINS + bbin] = off;
            off += v[k];
            if (bbin == NBINS - 1) starts[g * (NBINS + 1) + NBINS] = off;
        }
    }
}

// ---------------------------------------------------------------------------
// Kernel 2: reorder points into abs-bin-sorted payloads (no mins needed):
// float4(fx, fy, fz, bits((ly+64) | (lz+64)<<16)) at sorted[cb*NPTS + slot].
// 4 points/thread via 3x float4 loads. 1024 blocks x 256 thr.
// ---------------------------------------------------------------------------
__global__ void __launch_bounds__(256)
reorder_kernel(const float* __restrict__ pc,
               const float* __restrict__ gc,
               int* __restrict__ cursor,
               float4* __restrict__ sorted) {
    int gtid = blockIdx.x * 256 + threadIdx.x;     // 262144 threads, 4 pts each
    const float s = SCALE * 0.5f;
    const float* src = (gtid < 131072) ? pc : gc;
    int q = gtid & 131071;
    const fx4* p4 = (const fx4*)src;
    fx4 a = p4[3 * q], b = p4[3 * q + 1], c = p4[3 * q + 2];

    int cb = (gtid * 4) >> 15;            // all 4 points share one cb
    float4* dst = sorted + (size_t)cb * NPTS;
    int* cur = cursor + cb * NBINS;

    float xs[4] = {a.x, a.w, b.z, c.y};
    float ys[4] = {a.y, b.x, b.w, c.z};
    float zs[4] = {a.z, b.y, c.x, c.w};
    #pragma unroll
    for (int k = 0; k < 4; ++k) {
        float x = xs[k] * s, y = ys[k] * s, z = zs[k] * s;
        if (x + y + z == 0.0f) continue;
        int lx = (int)floorf(x), ly = (int)floorf(y), lz = (int)floorf(z);
        float fx = x - (float)lx, fy = y - (float)ly, fz = z - (float)lz;
        int slot = atomicAdd(&cur[lx + 64], 1);
        dst[slot] =
            make_float4(fx, fy, fz, __int_as_float((ly + 64) | ((lz + 64) << 16)));
    }
}

// ---------------------------------------------------------------------------
// Kernel 3: gather. One 1024-thread block per (cb, ix): accumulate the full
// 131x131 slab in LDS from abs bins (ix-2+minoffx) [w=fx] and (ix-1+minoffx)
// [w=1-fx] -- every point visit does useful work (no y-half bounds waste) --
// then stream the slab out once as float4 nontemporal stores (SHIFT-aligned).
// 68.7 KB LDS -> 2 blocks/CU -> 32 waves/CU.
// ---------------------------------------------------------------------------
__global__ void __launch_bounds__(1024)
gather_kernel(const float4* __restrict__ sorted,
              const int* __restrict__ starts,
              const int* __restrict__ mins,
              float* __restrict__ out) {
    __shared__ __align__(16) float tile[TILE_PAD];

    // bijective XCD-chunk swizzle: 4192 blocks = 8 * 524 exactly.
    int orig = blockIdx.x;
    int blk = (orig & 7) * 524 + (orig >> 3);

    int cb = blk / GRID_L;
    int ix = blk - cb * GRID_L;

    int base_dw = cb * GRID_V + ix * SLAB;
    int SHIFT = base_dw & 3;              // tile shift so vector body is aligned
    int i0 = (4 - SHIFT) & 3;             // first out index with 16B alignment

    int minoffx = mins[0] + 64;           // abs-bin of the global min corner
    int minoffy = mins[1] + 64;
    int minoffz = mins[2] + 64;

    fx4* tz = (fx4*)tile;
    for (int t = threadIdx.x; t < TILE_PAD / 4; t += 1024)
        tz[t] = (fx4){0.0f, 0.0f, 0.0f, 0.0f};
    __syncthreads();

    const float4* pts = sorted + (size_t)cb * NPTS;
    const int* st = starts + cb * (NBINS + 1);

    #pragma unroll
    for (int pass = 0; pass < 2; ++pass) {
        int bin = ix - 2 + pass + minoffx;
        if (bin < 0 || bin >= NBINS) continue;
        int b0 = st[bin], b1 = st[bin + 1];
        for (int p = b0 + (int)threadIdx.x; p < b1; p += 1024) {
            float4 q = pts[p];
            int pack = __float_as_int(q.w);
            int py = (pack & 0xffff) - minoffy + 1;   // lower y vertex, [1,129]
            int pz = (pack >> 16) - minoffz + 1;      // lower z vertex, [1,129]
            float wx  = pass ? (1.0f - q.x) : q.x;
            float wy0 = (1.0f - q.y) * wx;
            float wy1 = q.y * wx;
            float wz0 = 1.0f - q.z;
            float wz1 = q.z;
            float* t0 = &tile[py * GRID_L + pz + SHIFT];
            atomicAdd(t0,              wy0 * wz0);
            atomicAdd(t0 + 1,          wy0 * wz1);
            atomicAdd(t0 + GRID_L,     wy1 * wz0);
            atomicAdd(t0 + GRID_L + 1, wy1 * wz1);
        }
    }
    __syncthreads();

    float* o = out + base_dw;
    // head peel (<=3 scalar stores) to reach 16B alignment
    if ((int)threadIdx.x < i0)
        __builtin_nontemporal_store(tile[threadIdx.x + SHIFT], &o[threadIdx.x]);
    // vector body: LDS source at tile[i0+SHIFT] is 16B aligned
    int n4 = (SLAB - i0) >> 2;
    const fx4* t4 = (const fx4*)&tile[i0 + SHIFT];
    fx4* o4 = (fx4*)&o[i0];
    for (int k = threadIdx.x; k < n4; k += 1024)
        __builtin_nontemporal_store(t4[k], &o4[k]);
    // tail peel (<=3 scalar stores)
    int tail0 = i0 + 4 * n4;
    int tt = tail0 + (int)threadIdx.x;
    if (tt < SLAB)
        __builtin_nontemporal_store(tile[tt + SHIFT], &o[tt]);
}

extern "C" void kernel_launch(void* const* d_in, const int* in_sizes, int n_in,
                              void* d_out, int out_size, void* d_ws, size_t ws_size,
                              hipStream_t stream) {
    const float* pred = (const float*)d_in[0];
    const float* gt   = (const float*)d_in[1];
    float* out = (float*)d_out;   // [2, BATCH, GRID_V]: pred grids then gt grids

    // workspace layout
    char* w = (char*)d_ws;
    int* mins   = (int*)w;                         // 3 ints
    int* counts = (int*)(w + 16);                  // NCB*NBINS
    int* done   = counts + NCB * NBINS;            // 1 int (ticket)
    int* starts = done + 1;                        // NCB*(NBINS+1)
    int* cursor = starts + NCB * (NBINS + 1);      // NCB*NBINS
    size_t off = 16 + sizeof(int) *
        (size_t)(NCB * NBINS + 1 + NCB * (NBINS + 1) + NCB * NBINS);
    off = (off + 15) & ~(size_t)15;
    float4* sorted = (float4*)(w + off);           // NCB*NPTS float4 = 16 MB

    hipMemsetAsync(mins, 0x7f, 3 * sizeof(int), stream);
    hipMemsetAsync(counts, 0, sizeof(int) * (NCB * NBINS + 1), stream);  // + done

    min_hist_scan_kernel<<<256, 1024, 0, stream>>>(pred, gt, mins, counts,
                                                   done, starts, cursor);
    reorder_kernel<<<1024, 256, 0, stream>>>(pred, gt, cursor, sorted);
    gather_kernel<<<NCB * GRID_L, 1024, 0, stream>>>(sorted, starts, mins, out);
}

// Round 7
// 368.382 us; speedup vs baseline: 1.1586x; 1.1586x over previous
//
#include <hip/hip_runtime.h>

#define SCALE 128
#define GRID_L 131                        // grid side
#define SLAB (GRID_L * GRID_L)            // 17161 floats per x-slab
#define GRID_V (GRID_L * GRID_L * GRID_L)
#define BATCH 16
#define NPTS 32768                        // points per sample (2^15)
#define NCB 32                            // 2 clouds x 16 samples
#define NBINS 132                         // abs x-bin storage stride (used: 0..128)
#define CAP 384                           // bucket capacity: mean 256 + 8 sigma

// half-slab tile: 66 rows x 131 cols, +3 shift pad, rounded to float4 multiple
#define HROWS 66
#define HTILE_PAD 8652

typedef float fx4 __attribute__((ext_vector_type(4)));   // nontemporal-store-compatible

// ---------------------------------------------------------------------------
// FUSED PATH kernel 1: single pass over all points.
//  - per-axis min (ALL points, incl. padding, per reference) -> atomicMin
//  - masked points: slot = atomicAdd(cnt[cb][binx]) -> payload into fixed-
//    capacity bucket at (cb*NBINS+binx)*CAP + slot.
// Replaces min_hist + scan + reorder (one point read instead of two, no
// serial scan, two fewer dispatch boundaries).
// 1024 blocks x 256 thr, 4 points/thread via 3x float4 loads.
// ---------------------------------------------------------------------------
__global__ void __launch_bounds__(256)
point_pass_kernel(const float* __restrict__ pc,
                  const float* __restrict__ gc,
                  int* __restrict__ mins,
                  int* __restrict__ cnt,
                  float4* __restrict__ buckets) {
    __shared__ int red[3 * 4];            // per-wave mins, 4 waves

    int gtid = blockIdx.x * 256 + threadIdx.x;     // 262144 threads, 4 pts each
    const float s = SCALE * 0.5f;
    const float* src = (gtid < 131072) ? pc : gc;
    int q = gtid & 131071;
    const fx4* p4 = (const fx4*)src;
    fx4 a = p4[3 * q], b = p4[3 * q + 1], c = p4[3 * q + 2];

    int cb = (gtid * 4) >> 15;            // all 4 points share one cb
    int* curcb = cnt + cb * NBINS;
    float4* dst = buckets + (size_t)cb * NBINS * CAP;

    float xs[4] = {a.x, a.w, b.z, c.y};
    float ys[4] = {a.y, b.x, b.w, c.z};
    float zs[4] = {a.z, b.y, c.x, c.w};
    int m0 = 0x7fffffff, m1 = 0x7fffffff, m2 = 0x7fffffff;
    #pragma unroll
    for (int k = 0; k < 4; ++k) {
        float x = xs[k] * s, y = ys[k] * s, z = zs[k] * s;
        int lx = (int)floorf(x), ly = (int)floorf(y), lz = (int)floorf(z);
        m0 = min(m0, lx); m1 = min(m1, ly); m2 = min(m2, lz);
        if (x + y + z != 0.0f) {
            float fx = x - (float)lx, fy = y - (float)ly, fz = z - (float)lz;
            int slot = atomicAdd(&curcb[lx + 64], 1);
            if (slot < CAP)               // safety clamp (P(overflow) ~ 1e-12)
                dst[(lx + 64) * CAP + slot] = make_float4(
                    fx, fy, fz, __int_as_float((ly + 64) | ((lz + 64) << 16)));
        }
    }

    // wave-64 min reduction (4 waves/block)
    #pragma unroll
    for (int off = 32; off > 0; off >>= 1) {
        m0 = min(m0, __shfl_down(m0, off));
        m1 = min(m1, __shfl_down(m1, off));
        m2 = min(m2, __shfl_down(m2, off));
    }
    int wave = threadIdx.x >> 6;
    if ((threadIdx.x & 63) == 0) {
        red[3 * wave + 0] = m0;
        red[3 * wave + 1] = m1;
        red[3 * wave + 2] = m2;
    }
    __syncthreads();
    if (threadIdx.x < 3) {
        int m = red[threadIdx.x];
        #pragma unroll
        for (int w = 1; w < 4; ++w) m = min(m, red[3 * w + threadIdx.x]);
        atomicMin(&mins[threadIdx.x], m);
    }
}

// ---------------------------------------------------------------------------
// LEGACY PATH (ws too small for buckets): R3's proven kernels, verbatim.
// ---------------------------------------------------------------------------
__global__ void __launch_bounds__(1024)
min_hist_kernel(const float* __restrict__ pc,
                const float* __restrict__ gc,
                int* __restrict__ mins,
                int* __restrict__ counts) {
    __shared__ int h[NBINS];
    __shared__ int red[3 * 16];

    for (int t = threadIdx.x; t < NBINS; t += 1024) h[t] = 0;
    __syncthreads();

    const float s = SCALE * 0.5f;
    int blk = blockIdx.x;
    const float* src = (blk < 128) ? pc : gc;
    int jbase = (blk & 127) * 4096;
    const fx4* p4 = (const fx4*)(src + (size_t)3 * jbase);
    int t3 = 3 * (int)threadIdx.x;
    fx4 a = p4[t3], b = p4[t3 + 1], c = p4[t3 + 2];

    float xs[4] = {a.x, a.w, b.z, c.y};
    float ys[4] = {a.y, b.x, b.w, c.z};
    float zs[4] = {a.z, b.y, c.x, c.w};
    int m0 = 0x7fffffff, m1 = 0x7fffffff, m2 = 0x7fffffff;
    #pragma unroll
    for (int k = 0; k < 4; ++k) {
        float x = xs[k] * s, y = ys[k] * s, z = zs[k] * s;
        int lx = (int)floorf(x), ly = (int)floorf(y), lz = (int)floorf(z);
        if (x + y + z != 0.0f) atomicAdd(&h[lx + 64], 1);
        m0 = min(m0, lx); m1 = min(m1, ly); m2 = min(m2, lz);
    }
    #pragma unroll
    for (int off = 32; off > 0; off >>= 1) {
        m0 = min(m0, __shfl_down(m0, off));
        m1 = min(m1, __shfl_down(m1, off));
        m2 = min(m2, __shfl_down(m2, off));
    }
    int wave = threadIdx.x >> 6;
    if ((threadIdx.x & 63) == 0) {
        red[3 * wave + 0] = m0;
        red[3 * wave + 1] = m1;
        red[3 * wave + 2] = m2;
    }
    __syncthreads();
    if (threadIdx.x < 3) {
        int m = red[threadIdx.x];
        #pragma unroll
        for (int w = 1; w < 16; ++w) m = min(m, red[3 * w + threadIdx.x]);
        atomicMin(&mins[threadIdx.x], m);
    }
    int cb = (blk >> 7) * 16 + ((blk & 127) >> 3);
    for (int t = threadIdx.x; t < NBINS; t += 1024) {
        int c2 = h[t];
        if (c2) atomicAdd(&counts[cb * NBINS + t], c2);
    }
}

__global__ void scan_kernel(const int* __restrict__ counts,
                            int* __restrict__ starts,
                            int* __restrict__ cursor) {
    int cb = threadIdx.x;
    if (cb >= NCB) return;
    int acc = 0;
    #pragma unroll 4
    for (int bin = 0; bin < NBINS; ++bin) {
        starts[cb * (NBINS + 1) + bin] = acc;
        cursor[cb * NBINS + bin] = acc;
        acc += counts[cb * NBINS + bin];
    }
    starts[cb * (NBINS + 1) + NBINS] = acc;
}

__global__ void __launch_bounds__(256)
reorder_kernel(const float* __restrict__ pc,
               const float* __restrict__ gc,
               int* __restrict__ cursor,
               float4* __restrict__ sorted) {
    int gtid = blockIdx.x * 256 + threadIdx.x;
    const float s = SCALE * 0.5f;
    const float* src = (gtid < 131072) ? pc : gc;
    int q = gtid & 131071;
    const fx4* p4 = (const fx4*)src;
    fx4 a = p4[3 * q], b = p4[3 * q + 1], c = p4[3 * q + 2];

    int cb = (gtid * 4) >> 15;
    float4* dst = sorted + (size_t)cb * NPTS;
    int* cur = cursor + cb * NBINS;

    float xs[4] = {a.x, a.w, b.z, c.y};
    float ys[4] = {a.y, b.x, b.w, c.z};
    float zs[4] = {a.z, b.y, c.x, c.w};
    #pragma unroll
    for (int k = 0; k < 4; ++k) {
        float x = xs[k] * s, y = ys[k] * s, z = zs[k] * s;
        if (x + y + z == 0.0f) continue;
        int lx = (int)floorf(x), ly = (int)floorf(y), lz = (int)floorf(z);
        float fx = x - (float)lx, fy = y - (float)ly, fz = z - (float)lz;
        int slot = atomicAdd(&cur[lx + 64], 1);
        dst[slot] =
            make_float4(fx, fy, fz, __int_as_float((ly + 64) | ((lz + 64) << 16)));
    }
}

// ---------------------------------------------------------------------------
// Gather (R3's y-half structure, unchanged): one 512-thread block per
// (cb, ix, y-half). BUCKET=true reads fixed-capacity buckets via cnt[];
// BUCKET=false reads dense sorted[] via starts[]. 34.6 KB LDS -> 4 blocks/CU.
// ---------------------------------------------------------------------------
template<bool BUCKET>
__global__ void __launch_bounds__(512)
gather_kernel(const float4* __restrict__ pts_base,
              const int* __restrict__ meta,
              const int* __restrict__ mins,
              float* __restrict__ out) {
    __shared__ __align__(16) float tile[HTILE_PAD];

    // bijective XCD-chunk swizzle: 8384 blocks = 8 * 1048 exactly.
    int orig = blockIdx.x;
    int blk = (orig & 7) * 1048 + (orig >> 3);

    int h  = blk & 1;
    int t2 = blk >> 1;                    // cb*GRID_L + ix
    int cb = t2 / GRID_L;
    int ix = t2 - cb * GRID_L;

    int base = HROWS * h;                 // first slab row owned by this block
    int rows = h ? (GRID_L - HROWS) : HROWS;   // 65 : 66
    int N = rows * GRID_L;                // floats to emit
    int base_dw = cb * GRID_V + ix * SLAB + base * GRID_L;
    int SHIFT = base_dw & 3;
    int i0 = (4 - SHIFT) & 3;

    int minoffx = mins[0] + 64;
    int minoffy = mins[1] + 64;
    int minoffz = mins[2] + 64;

    fx4* tz = (fx4*)tile;
    for (int t = threadIdx.x; t < HTILE_PAD / 4; t += 512)
        tz[t] = (fx4){0.0f, 0.0f, 0.0f, 0.0f};
    __syncthreads();

    const float4* pts = BUCKET ? pts_base : pts_base + (size_t)cb * NPTS;

    #pragma unroll
    for (int pass = 0; pass < 2; ++pass) {
        int bin = ix - 2 + pass + minoffx;
        if (bin < 0 || bin >= NBINS) continue;
        int b0, b1;
        if (BUCKET) {
            b0 = (cb * NBINS + bin) * CAP;
            int c = meta[cb * NBINS + bin];
            b1 = b0 + min(c, CAP);
        } else {
            const int* st = meta + cb * (NBINS + 1);
            b0 = st[bin]; b1 = st[bin + 1];
        }
        for (int p = b0 + (int)threadIdx.x; p < b1; p += 512) {
            float4 q = pts[p];
            int pack = __float_as_int(q.w);
            int py = (pack & 0xffff) - minoffy + 1;   // lower y vertex
            int pz = (pack >> 16) - minoffz + 1;      // lower z vertex
            float wx  = pass ? (1.0f - q.x) : q.x;
            float wz0 = wx * (1.0f - q.z);
            float wz1 = wx * q.z;
            int r0 = py - base;
            if (r0 >= 0 && r0 < rows) {
                float wy0 = 1.0f - q.y;
                float* t0 = &tile[r0 * GRID_L + pz + SHIFT];
                atomicAdd(t0,     wy0 * wz0);
                atomicAdd(t0 + 1, wy0 * wz1);
            }
            int r1 = r0 + 1;
            if (r1 >= 0 && r1 < rows) {
                float wy1 = q.y;
                float* t1 = &tile[r1 * GRID_L + pz + SHIFT];
                atomicAdd(t1,     wy1 * wz0);
                atomicAdd(t1 + 1, wy1 * wz1);
            }
        }
    }
    __syncthreads();

    float* o = out + base_dw;
    if ((int)threadIdx.x < i0)
        __builtin_nontemporal_store(tile[threadIdx.x + SHIFT], &o[threadIdx.x]);
    int n4 = (N - i0) >> 2;
    const fx4* t4 = (const fx4*)&tile[i0 + SHIFT];
    fx4* o4 = (fx4*)&o[i0];
    for (int k = threadIdx.x; k < n4; k += 512)
        __builtin_nontemporal_store(t4[k], &o4[k]);
    int tail0 = i0 + 4 * n4;
    int tt = tail0 + (int)threadIdx.x;
    if (tt < N)
        __builtin_nontemporal_store(tile[tt + SHIFT], &o[tt]);
}

extern "C" void kernel_launch(void* const* d_in, const int* in_sizes, int n_in,
                              void* d_out, int out_size, void* d_ws, size_t ws_size,
                              hipStream_t stream) {
    const float* pred = (const float*)d_in[0];
    const float* gt   = (const float*)d_in[1];
    float* out = (float*)d_out;   // [2, BATCH, GRID_V]: pred grids then gt grids

    char* w = (char*)d_ws;
    int* mins = (int*)w;                               // 3 ints (16B slot)

    // fused-path need: 16 + cnt(NCB*NBINS*4, pad to 16) + buckets
    size_t cnt_bytes = ((sizeof(int) * (size_t)(NCB * NBINS)) + 15) & ~(size_t)15;
    size_t bucket_bytes = sizeof(float4) * (size_t)NCB * NBINS * CAP;   // ~25.9 MB
    size_t need = 16 + cnt_bytes + bucket_bytes;

    if (ws_size >= need) {
        // -------- fused path: 2 dispatches --------
        int* cnt = (int*)(w + 16);
        float4* buckets = (float4*)(w + 16 + cnt_bytes);

        hipMemsetAsync(mins, 0x7f, 3 * sizeof(int), stream);
        hipMemsetAsync(cnt, 0, sizeof(int) * NCB * NBINS, stream);

        point_pass_kernel<<<1024, 256, 0, stream>>>(pred, gt, mins, cnt, buckets);
        gather_kernel<true><<<NCB * GRID_L * 2, 512, 0, stream>>>(
            buckets, cnt, mins, out);
    } else {
        // -------- legacy R3 path: 4 dispatches --------
        int* counts = (int*)(w + 16);                  // NCB*NBINS
        int* starts = counts + NCB * NBINS;            // NCB*(NBINS+1)
        int* cursor = starts + NCB * (NBINS + 1);      // NCB*NBINS
        size_t off = 16 + sizeof(int) *
            (size_t)(NCB * NBINS + NCB * (NBINS + 1) + NCB * NBINS);
        off = (off + 15) & ~(size_t)15;
        float4* sorted = (float4*)(w + off);           // NCB*NPTS float4 = 16 MB

        hipMemsetAsync(mins, 0x7f, 3 * sizeof(int), stream);
        hipMemsetAsync(counts, 0, sizeof(int) * NCB * NBINS, stream);

        min_hist_kernel<<<256, 1024, 0, stream>>>(pred, gt, mins, counts);
        scan_kernel<<<1, 64, 0, stream>>>(counts, starts, cursor);
        reorder_kernel<<<1024, 256, 0, stream>>>(pred, gt, cursor, sorted);
        gather_kernel<false><<<NCB * GRID_L * 2, 512, 0, stream>>>(
            sorted, starts, mins, out);
    }
}

// Round 8
// 329.345 us; speedup vs baseline: 1.2959x; 1.1185x over previous
//
#include <hip/hip_runtime.h>

#define SCALE 128
#define GRID_L 131                        // grid side
#define SLAB (GRID_L * GRID_L)            // 17161 floats per x-slab
#define GRID_V (GRID_L * GRID_L * GRID_L)
#define BATCH 16
#define NPTS 32768                        // points per sample (2^15)
#define NCB 32                            // 2 clouds x 16 samples
#define NBINS 132                        // abs x-bin storage stride (used: 0..128)
#define CAP 384                           // bucket capacity: mean 256 + 8 sigma

// half-slab tile: 66 rows x 131 cols, +3 shift pad, rounded to float4 multiple
#define HROWS 66
#define HTILE_PAD 8652

typedef float fx4 __attribute__((ext_vector_type(4)));   // nontemporal-store-compatible

// ---------------------------------------------------------------------------
// FUSED PATH kernel 1: single pass over all points with BLOCK-AGGREGATED
// slot reservation. Per 512-thread block (2048 contiguous points, one cb):
//   phase 1: LDS histogram atomicAdd returns per-point local slot
//   phase 2: ONE global atomicAdd per (block,bin) reserves a contiguous range
//            (512 blocks x 132 bins ~ 68K global atomics vs 1M per-point --
//            attacks L2 same-line atomic serialization)
//   phase 3: payload stored at bucket[bin]*CAP + gbase[bin] + lslot
// Also computes per-axis min (ALL points, incl. padding, per reference).
// ---------------------------------------------------------------------------
__global__ void __launch_bounds__(512)
point_pass_kernel(const float* __restrict__ pc,
                  const float* __restrict__ gc,
                  int* __restrict__ mins,
                  int* __restrict__ cnt,
                  float4* __restrict__ buckets) {
    __shared__ int lh[NBINS];             // per-block bin counts
    __shared__ int gbase[NBINS];          // reserved global base per bin
    __shared__ int red[3 * 8];            // per-wave mins, 8 waves

    for (int t = threadIdx.x; t < NBINS; t += 512) lh[t] = 0;
    __syncthreads();

    const float s = SCALE * 0.5f;
    int blk = blockIdx.x;                 // 512 blocks, 2048 pts each, 16/cb
    int cb = blk >> 4;                    // 0..15 pred, 16..31 gt
    const float* src = (cb < 16) ? pc : gc;
    int sample = cb & 15;
    int g = ((sample * NPTS + (blk & 15) * 2048) >> 2) + (int)threadIdx.x;
    const fx4* p4 = (const fx4*)src;
    fx4 a = p4[3 * g], b = p4[3 * g + 1], c = p4[3 * g + 2];

    int* cntcb = cnt + cb * NBINS;
    float4* dst = buckets + (size_t)cb * NBINS * CAP;

    float xs[4] = {a.x, a.w, b.z, c.y};
    float ys[4] = {a.y, b.x, b.w, c.z};
    float zs[4] = {a.z, b.y, c.x, c.w};
    int bins[4], lslot[4];
    float4 pay[4];
    int m0 = 0x7fffffff, m1 = 0x7fffffff, m2 = 0x7fffffff;
    #pragma unroll
    for (int k = 0; k < 4; ++k) {
        float x = xs[k] * s, y = ys[k] * s, z = zs[k] * s;
        int lx = (int)floorf(x), ly = (int)floorf(y), lz = (int)floorf(z);
        m0 = min(m0, lx); m1 = min(m1, ly); m2 = min(m2, lz);
        if (x + y + z != 0.0f) {
            float fx = x - (float)lx, fy = y - (float)ly, fz = z - (float)lz;
            bins[k] = lx + 64;
            lslot[k] = atomicAdd(&lh[bins[k]], 1);
            pay[k] = make_float4(
                fx, fy, fz, __int_as_float((ly + 64) | ((lz + 64) << 16)));
        } else {
            bins[k] = -1;
        }
    }
    __syncthreads();

    // phase 2: bulk reservation, one global atomic per non-empty (block,bin)
    for (int t = threadIdx.x; t < NBINS; t += 512) {
        int c2 = lh[t];
        gbase[t] = c2 ? atomicAdd(&cntcb[t], c2) : 0;
    }
    __syncthreads();

    // phase 3: payload writes
    #pragma unroll
    for (int k = 0; k < 4; ++k) {
        if (bins[k] >= 0) {
            int slot = gbase[bins[k]] + lslot[k];
            if (slot < CAP)               // clamp (P(overflow) ~ 1e-12)
                dst[bins[k] * CAP + slot] = pay[k];
        }
    }

    // wave-64 min reduction (8 waves/block)
    #pragma unroll
    for (int off = 32; off > 0; off >>= 1) {
        m0 = min(m0, __shfl_down(m0, off));
        m1 = min(m1, __shfl_down(m1, off));
        m2 = min(m2, __shfl_down(m2, off));
    }
    int wave = threadIdx.x >> 6;
    if ((threadIdx.x & 63) == 0) {
        red[3 * wave + 0] = m0;
        red[3 * wave + 1] = m1;
        red[3 * wave + 2] = m2;
    }
    __syncthreads();
    if (threadIdx.x < 3) {
        int m = red[threadIdx.x];
        #pragma unroll
        for (int w = 1; w < 8; ++w) m = min(m, red[3 * w + threadIdx.x]);
        atomicMin(&mins[threadIdx.x], m);
    }
}

// ---------------------------------------------------------------------------
// LEGACY PATH (ws too small for buckets): R3's proven kernels, verbatim.
// ---------------------------------------------------------------------------
__global__ void __launch_bounds__(1024)
min_hist_kernel(const float* __restrict__ pc,
                const float* __restrict__ gc,
                int* __restrict__ mins,
                int* __restrict__ counts) {
    __shared__ int h[NBINS];
    __shared__ int red[3 * 16];

    for (int t = threadIdx.x; t < NBINS; t += 1024) h[t] = 0;
    __syncthreads();

    const float s = SCALE * 0.5f;
    int blk = blockIdx.x;
    const float* src = (blk < 128) ? pc : gc;
    int jbase = (blk & 127) * 4096;
    const fx4* p4 = (const fx4*)(src + (size_t)3 * jbase);
    int t3 = 3 * (int)threadIdx.x;
    fx4 a = p4[t3], b = p4[t3 + 1], c = p4[t3 + 2];

    float xs[4] = {a.x, a.w, b.z, c.y};
    float ys[4] = {a.y, b.x, b.w, c.z};
    float zs[4] = {a.z, b.y, c.x, c.w};
    int m0 = 0x7fffffff, m1 = 0x7fffffff, m2 = 0x7fffffff;
    #pragma unroll
    for (int k = 0; k < 4; ++k) {
        float x = xs[k] * s, y = ys[k] * s, z = zs[k] * s;
        int lx = (int)floorf(x), ly = (int)floorf(y), lz = (int)floorf(z);
        if (x + y + z != 0.0f) atomicAdd(&h[lx + 64], 1);
        m0 = min(m0, lx); m1 = min(m1, ly); m2 = min(m2, lz);
    }
    #pragma unroll
    for (int off = 32; off > 0; off >>= 1) {
        m0 = min(m0, __shfl_down(m0, off));
        m1 = min(m1, __shfl_down(m1, off));
        m2 = min(m2, __shfl_down(m2, off));
    }
    int wave = threadIdx.x >> 6;
    if ((threadIdx.x & 63) == 0) {
        red[3 * wave + 0] = m0;
        red[3 * wave + 1] = m1;
        red[3 * wave + 2] = m2;
    }
    __syncthreads();
    if (threadIdx.x < 3) {
        int m = red[threadIdx.x];
        #pragma unroll
        for (int w = 1; w < 16; ++w) m = min(m, red[3 * w + threadIdx.x]);
        atomicMin(&mins[threadIdx.x], m);
    }
    int cb = (blk >> 7) * 16 + ((blk & 127) >> 3);
    for (int t = threadIdx.x; t < NBINS; t += 1024) {
        int c2 = h[t];
        if (c2) atomicAdd(&counts[cb * NBINS + t], c2);
    }
}

__global__ void scan_kernel(const int* __restrict__ counts,
                            int* __restrict__ starts,
                            int* __restrict__ cursor) {
    int cb = threadIdx.x;
    if (cb >= NCB) return;
    int acc = 0;
    #pragma unroll 4
    for (int bin = 0; bin < NBINS; ++bin) {
        starts[cb * (NBINS + 1) + bin] = acc;
        cursor[cb * NBINS + bin] = acc;
        acc += counts[cb * NBINS + bin];
    }
    starts[cb * (NBINS + 1) + NBINS] = acc;
}

__global__ void __launch_bounds__(256)
reorder_kernel(const float* __restrict__ pc,
               const float* __restrict__ gc,
               int* __restrict__ cursor,
               float4* __restrict__ sorted) {
    int gtid = blockIdx.x * 256 + threadIdx.x;
    const float s = SCALE * 0.5f;
    const float* src = (gtid < 131072) ? pc : gc;
    int q = gtid & 131071;
    const fx4* p4 = (const fx4*)src;
    fx4 a = p4[3 * q], b = p4[3 * q + 1], c = p4[3 * q + 2];

    int cb = (gtid * 4) >> 15;
    float4* dst = sorted + (size_t)cb * NPTS;
    int* cur = cursor + cb * NBINS;

    float xs[4] = {a.x, a.w, b.z, c.y};
    float ys[4] = {a.y, b.x, b.w, c.z};
    float zs[4] = {a.z, b.y, c.x, c.w};
    #pragma unroll
    for (int k = 0; k < 4; ++k) {
        float x = xs[k] * s, y = ys[k] * s, z = zs[k] * s;
        if (x + y + z == 0.0f) continue;
        int lx = (int)floorf(x), ly = (int)floorf(y), lz = (int)floorf(z);
        float fx = x - (float)lx, fy = y - (float)ly, fz = z - (float)lz;
        int slot = atomicAdd(&cur[lx + 64], 1);
        dst[slot] =
            make_float4(fx, fy, fz, __int_as_float((ly + 64) | ((lz + 64) << 16)));
    }
}

// ---------------------------------------------------------------------------
// Gather (unchanged): one 512-thread block per (cb, ix, y-half).
// BUCKET=true reads fixed-capacity buckets via cnt[]; BUCKET=false reads
// dense sorted[] via starts[]. 34.6 KB LDS -> 4 blocks/CU.
// ---------------------------------------------------------------------------
template<bool BUCKET>
__global__ void __launch_bounds__(512)
gather_kernel(const float4* __restrict__ pts_base,
              const int* __restrict__ meta,
              const int* __restrict__ mins,
              float* __restrict__ out) {
    __shared__ __align__(16) float tile[HTILE_PAD];

    // bijective XCD-chunk swizzle: 8384 blocks = 8 * 1048 exactly.
    int orig = blockIdx.x;
    int blk = (orig & 7) * 1048 + (orig >> 3);

    int h  = blk & 1;
    int t2 = blk >> 1;                    // cb*GRID_L + ix
    int cb = t2 / GRID_L;
    int ix = t2 - cb * GRID_L;

    int base = HROWS * h;                 // first slab row owned by this block
    int rows = h ? (GRID_L - HROWS) : HROWS;   // 65 : 66
    int N = rows * GRID_L;                // floats to emit
    int base_dw = cb * GRID_V + ix * SLAB + base * GRID_L;
    int SHIFT = base_dw & 3;
    int i0 = (4 - SHIFT) & 3;

    int minoffx = mins[0] + 64;
    int minoffy = mins[1] + 64;
    int minoffz = mins[2] + 64;

    fx4* tz = (fx4*)tile;
    for (int t = threadIdx.x; t < HTILE_PAD / 4; t += 512)
        tz[t] = (fx4){0.0f, 0.0f, 0.0f, 0.0f};
    __syncthreads();

    const float4* pts = BUCKET ? pts_base : pts_base + (size_t)cb * NPTS;

    #pragma unroll
    for (int pass = 0; pass < 2; ++pass) {
        int bin = ix - 2 + pass + minoffx;
        if (bin < 0 || bin >= NBINS) continue;
        int b0, b1;
        if (BUCKET) {
            b0 = (cb * NBINS + bin) * CAP;
            int c = meta[cb * NBINS + bin];
            b1 = b0 + min(c, CAP);
        } else {
            const int* st = meta + cb * (NBINS + 1);
            b0 = st[bin]; b1 = st[bin + 1];
        }
        for (int p = b0 + (int)threadIdx.x; p < b1; p += 512) {
            float4 q = pts[p];
            int pack = __float_as_int(q.w);
            int py = (pack & 0xffff) - minoffy + 1;   // lower y vertex
            int pz = (pack >> 16) - minoffz + 1;      // lower z vertex
            float wx  = pass ? (1.0f - q.x) : q.x;
            float wz0 = wx * (1.0f - q.z);
            float wz1 = wx * q.z;
            int r0 = py - base;
            if (r0 >= 0 && r0 < rows) {
                float wy0 = 1.0f - q.y;
                float* t0 = &tile[r0 * GRID_L + pz + SHIFT];
                atomicAdd(t0,     wy0 * wz0);
                atomicAdd(t0 + 1, wy0 * wz1);
            }
            int r1 = r0 + 1;
            if (r1 >= 0 && r1 < rows) {
                float wy1 = q.y;
                float* t1 = &tile[r1 * GRID_L + pz + SHIFT];
                atomicAdd(t1,     wy1 * wz0);
                atomicAdd(t1 + 1, wy1 * wz1);
            }
        }
    }
    __syncthreads();

    float* o = out + base_dw;
    if ((int)threadIdx.x < i0)
        __builtin_nontemporal_store(tile[threadIdx.x + SHIFT], &o[threadIdx.x]);
    int n4 = (N - i0) >> 2;
    const fx4* t4 = (const fx4*)&tile[i0 + SHIFT];
    fx4* o4 = (fx4*)&o[i0];
    for (int k = threadIdx.x; k < n4; k += 512)
        __builtin_nontemporal_store(t4[k], &o4[k]);
    int tail0 = i0 + 4 * n4;
    int tt = tail0 + (int)threadIdx.x;
    if (tt < N)
        __builtin_nontemporal_store(tile[tt + SHIFT], &o[tt]);
}

extern "C" void kernel_launch(void* const* d_in, const int* in_sizes, int n_in,
                              void* d_out, int out_size, void* d_ws, size_t ws_size,
                              hipStream_t stream) {
    const float* pred = (const float*)d_in[0];
    const float* gt   = (const float*)d_in[1];
    float* out = (float*)d_out;   // [2, BATCH, GRID_V]: pred grids then gt grids

    char* w = (char*)d_ws;
    int* mins = (int*)w;                               // 3 ints (16B slot)

    // fused-path need: 16 + cnt(NCB*NBINS*4, pad to 16) + buckets
    size_t cnt_bytes = ((sizeof(int) * (size_t)(NCB * NBINS)) + 15) & ~(size_t)15;
    size_t bucket_bytes = sizeof(float4) * (size_t)NCB * NBINS * CAP;   // ~25.9 MB
    size_t need = 16 + cnt_bytes + bucket_bytes;

    if (ws_size >= need) {
        // -------- fused path: 2 dispatches --------
        int* cnt = (int*)(w + 16);
        float4* buckets = (float4*)(w + 16 + cnt_bytes);

        hipMemsetAsync(mins, 0x7f, 3 * sizeof(int), stream);
        hipMemsetAsync(cnt, 0, sizeof(int) * NCB * NBINS, stream);

        point_pass_kernel<<<512, 512, 0, stream>>>(pred, gt, mins, cnt, buckets);
        gather_kernel<true><<<NCB * GRID_L * 2, 512, 0, stream>>>(
            buckets, cnt, mins, out);
    } else {
        // -------- legacy R3 path: 4 dispatches --------
        int* counts = (int*)(w + 16);                  // NCB*NBINS
        int* starts = counts + NCB * NBINS;            // NCB*(NBINS+1)
        int* cursor = starts + NCB * (NBINS + 1);      // NCB*NBINS
        size_t off = 16 + sizeof(int) *
            (size_t)(NCB * NBINS + NCB * (NBINS + 1) + NCB * NBINS);
        off = (off + 15) & ~(size_t)15;
        float4* sorted = (float4*)(w + off);           // NCB*NPTS float4 = 16 MB

        hipMemsetAsync(mins, 0x7f, 3 * sizeof(int), stream);
        hipMemsetAsync(counts, 0, sizeof(int) * NCB * NBINS, stream);

        min_hist_kernel<<<256, 1024, 0, stream>>>(pred, gt, mins, counts);
        scan_kernel<<<1, 64, 0, stream>>>(counts, starts, cursor);
        reorder_kernel<<<1024, 256, 0, stream>>>(pred, gt, cursor, sorted);
        gather_kernel<false><<<NCB * GRID_L * 2, 512, 0, stream>>>(
            sorted, starts, mins, out);
    }
}